// Round 9
// baseline (702.916 us; speedup 1.0000x reference)
//
#include <hip/hip_runtime.h>
#include <hip/hip_bf16.h>

#define BB 32
#define LL 128
#define DD 400
#define KK 40
#define EE 416   // e padded to 13*32
#define SDN 50   // d-slot count (400/8)
#define SEN 52   // e-slot count (416/8)

typedef __attribute__((ext_vector_type(8)))  short  bfrag;   // 8 bf16 = 4 VGPRs
typedef __attribute__((ext_vector_type(16))) float  ffrag;   // 16 fp32 acc

static __device__ __forceinline__ short f2bf(float f) {
    union { float f; unsigned u; } v; v.f = f;
    unsigned r = (v.u + 0x7FFF + ((v.u >> 16) & 1)) >> 16;
    return (short)r;
}

#define MFMA32(a, b, c) __builtin_amdgcn_mfma_f32_32x32x16_bf16((a), (b), (c), 0, 0, 0)

static __device__ __forceinline__ void fzero(ffrag& f) {
#pragma unroll
    for (int r = 0; r < 16; ++r) f[r] = 0.f;
}

// ---------------------------------------------------------------------------
// Fused prep: Hslots[b][sd][h][8], Cslots[b][se][c][8] (zero-pad e>=400),
//             Uslots[k][sd][e][8] (zero-pad e>=400).
// ---------------------------------------------------------------------------
__global__ __launch_bounds__(256) void p_prep(
    const float* __restrict__ H, const float* __restrict__ C,
    const float* __restrict__ U,
    short* __restrict__ Hs, short* __restrict__ Cs, short* __restrict__ Us)
{
    int id = blockIdx.x * 256 + threadIdx.x;
    if (id < BB*SDN*LL) {
        int b = id / (SDN*LL); int r = id % (SDN*LL);
        int sd = r / LL; int h = r % LL;
        const float* src = H + ((size_t)(b*LL + h))*DD + sd*8;
        bfrag v;
#pragma unroll
        for (int j = 0; j < 8; ++j) v[j] = f2bf(src[j]);
        *(bfrag*)(Hs + (size_t)id*8) = v;
    } else if (id < BB*SDN*LL + BB*SEN*LL) {
        id -= BB*SDN*LL;
        int b = id / (SEN*LL); int r = id % (SEN*LL);
        int se = r / LL; int c = r % LL;
        bfrag v;
#pragma unroll
        for (int j = 0; j < 8; ++j) {
            int e = se*8 + j;
            v[j] = (e < DD) ? f2bf(C[((size_t)(b*LL + c))*DD + e]) : (short)0;
        }
        *(bfrag*)(Cs + (size_t)id*8) = v;
    } else {
        id -= BB*SDN*LL + BB*SEN*LL;      // < 40*50*416
        int k = id / (SDN*EE); int r = id % (SDN*EE);
        int sd = r / EE; int e = r % EE;
        bfrag v;
#pragma unroll
        for (int j = 0; j < 8; ++j)
            v[j] = (e < DD) ? f2bf(U[((size_t)k*DD + sd*8 + j)*DD + e]) : (short)0;
        *(bfrag*)(Us + (size_t)id*8) = v;
    }
}

// ---------------------------------------------------------------------------
// SD/SE (round-2-verified body). Also zeroes tgt and the Dg colsum
// accumulator (both consumed later in the stream).
// ---------------------------------------------------------------------------
__global__ __launch_bounds__(256) void k_sdse(
    const float* __restrict__ H, const float* __restrict__ C,
    const float* __restrict__ Wd, const float* __restrict__ We,
    float* __restrict__ SD, float* __restrict__ SE,
    float* __restrict__ tgt, float* __restrict__ Dgw)
{
    const int b   = blockIdx.x;
    const int rg  = blockIdx.y;
    const int srcC = blockIdx.z;
    const int t = threadIdx.x;

    if (srcC == 0) {
        if (rg == 0 && t == 0) tgt[b] = 0.f;
        if (t < 32) Dgw[b*128 + rg*32 + t] = 0.f;
    }

    __shared__ float Wl[KK*DD];      // 64 KB
    {
        const float4* Wsrc = (const float4*)(srcC ? We : Wd);
        for (int i = t; i < KK*DD/4; i += 256) ((float4*)Wl)[i] = Wsrc[i];
    }
    __syncthreads();

    const int task = t >> 3;
    const int p    = t & 7;
    const int row  = rg*32 + task;
    const float* X = (srcC ? C : H) + ((size_t)(b*LL + row))*DD + p*50;

    float2 x[25];
#pragma unroll
    for (int i = 0; i < 25; ++i) x[i] = ((const float2*)X)[i];

    float* out = (srcC ? SE : SD) + (size_t)b*KK*LL + row;
    const float* Wb = Wl + p*50;

    for (int k = 0; k < KK; ++k) {
        const float2* wp = (const float2*)(Wb + k*DD);
        float s0 = 0.f, s1 = 0.f;
#pragma unroll
        for (int i = 0; i < 24; i += 2) {
            float2 w0 = wp[i], w1 = wp[i+1];
            s0 = fmaf(x[i].x,   w0.x, s0); s0 = fmaf(x[i].y,   w0.y, s0);
            s1 = fmaf(x[i+1].x, w1.x, s1); s1 = fmaf(x[i+1].y, w1.y, s1);
        }
        { float2 w0 = wp[24]; s0 = fmaf(x[24].x, w0.x, s0); s0 = fmaf(x[24].y, w0.y, s0); }
        float s = s0 + s1;
        s += __shfl_xor(s, 1); s += __shfl_xor(s, 2); s += __shfl_xor(s, 4);
        if (p == 0) out[k*LL] = s;
    }
}

// T-write: scatter one 32x32 T-tile into phase-2 A-fragment layout
// [s_e][h][8] as 4 x ds_write_b64 (round-8 verified). Skips e>=400.
static __device__ __forceinline__ void t_write(
    short* __restrict__ Ping, const ffrag& T, int et, int ht, int l31, int kh)
{
#pragma unroll
    for (int q = 0; q < 4; ++q) {
        const int e_base = 32*et + 8*q + 4*kh;   // e_loc = e_base + (0..3)
        if (e_base < DD) {
            const int r = 4*q;
            uint2 v;
            v.x = (unsigned)(unsigned short)f2bf(T[r])
                | ((unsigned)(unsigned short)f2bf(T[r+1]) << 16);
            v.y = (unsigned)(unsigned short)f2bf(T[r+2])
                | ((unsigned)(unsigned short)f2bf(T[r+3]) << 16);
            *(uint2*)(&Ping[((size_t)(e_base>>3)*LL + 32*ht + l31)*8 + (e_base&7)]) = v;
        }
    }
}

// ---------------------------------------------------------------------------
// Main MFMA kernel, round 9. Round-5/8 shell (grid (32 b, 8 g), 1024 thr,
// 1 block/CU, XCD = b%8, Ping 102.4 KB); inner loops restructured:
//   Phase 1: 2e x 2h outer product per wave (waves 0..13): per K-step
//     2 LDS + 2 global frags feed 4 MFMAs (was 4 LDS + 1 global per 4 MFMA)
//     -> LDS reads/k 1300 -> 700, and ALL operands prefetched one full
//     step ahead (round-8's half-pipeline left T2/T3 reads un-hidden).
//   Phase 2: CPF 6-deep / TAF 3-deep rotation (was 3/2) to cover L2 lat.
// ---------------------------------------------------------------------------
__global__ __launch_bounds__(1024) void k_mfma(
    const short* __restrict__ Hs, const short* __restrict__ Cs,
    const short* __restrict__ Us,
    const float* __restrict__ SD, const float* __restrict__ SE,
    const float* __restrict__ bvec, const float* __restrict__ mask,
    const int* __restrict__ heads, const int* __restrict__ tags,
    float* __restrict__ A8, float* __restrict__ tgt)
{
    const int b  = blockIdx.x;     // fast dim -> XCD = b % 8
    const int g  = blockIdx.y;     // k-group
    const int t  = threadIdx.x;
    const int w  = t >> 6;         // 0..15
    const int l31 = t & 31;
    const int kh  = (t >> 5) & 1;  // K-half of MFMA operands

    __shared__ short Ping[SDN*LL*8];    // 102,400 B : Hs stage <-> Tbuf

    const size_t hsB = (size_t)b * SDN * LL;
    const size_t csB = (size_t)b * SEN * LL;

    // ---- phase-1 roles ----
    const int ep = w >> 1;             // e-pair 0..6 (w<14)
    const int hp = w & 1;              // h-pair 0..1
    const bool p1on = (w < 14);
    const bool has1 = (ep < 6);        // second e-tile valid

    // ---- phase-2 roles & k-invariant epilogue constants ----
    const int ht2 = w >> 2;            // h-tile 0..3
    const int ct  = w & 3;             // c-tile 0..3
    const int hbase = 32*ht2 + 4*kh;
    const int c0 = 32*ct + l31;
    const float mc0 = mask[b*LL + c0];
    const int head0 = heads[b*LL + c0];
    const int tag0  = tags[b*LL + c0];
    unsigned vb = 0;
#pragma unroll
    for (int r = 0; r < 16; ++r) {
        const int hr = hbase + (r&3) + 8*(r>>2);
        if (mask[b*LL + hr] != 0.f && mc0 != 0.f && hr != c0) vb |= 1u << r;
    }

    ffrag E; fzero(E);

    for (int kk = 0; kk < 5; ++kk) {
        const int k = g + 8*kk;

        __syncthreads();   // prev phase 2 done reading Ping

        // ---- stage Hs[b] -> Ping (102.4 KB straight copy; L2-resident) ----
        {
            const uint4* src = (const uint4*)(Hs + hsB*8);
            uint4* dst = (uint4*)Ping;
            for (int i = t; i < SDN*LL*8*2/16; i += 1024) dst[i] = src[i];
        }
        __syncthreads();

        // ---- Phase 1: wave computes 2x2 T-tiles (et 2ep..2ep+1, ht 2hp..) --
        ffrag T00, T01, T10, T11;
        if (p1on) {
            fzero(T00); fzero(T01); fzero(T10); fzero(T11);
            const short* up0 = Us + (((size_t)k*SDN + kh)*EE + 32*(2*ep) + l31)*8;
            const short* hb  = Ping + ((size_t)kh*LL + 64*hp + l31)*8;
#define U0F(j) (*(const bfrag*)(up0 + (size_t)(j)*(2*EE*8)))
#define U1F(j) (*(const bfrag*)(up0 + 32*8 + (size_t)(j)*(2*EE*8)))
#define H0F(j) (*(const bfrag*)(hb + (size_t)(2*(j))*(LL*8)))
#define H1F(j) (*(const bfrag*)(hb + 32*8 + (size_t)(2*(j))*(LL*8)))
            bfrag a0A = U0F(0), a0B = U0F(1);
            bfrag a1A = a0A, a1B = a0B;
            if (has1) { a1A = U1F(0); a1B = U1F(1); }
            bfrag h0 = H0F(0), h1 = H1F(0);
#pragma unroll 1
            for (int j = 0; j < 23; ++j) {
                bfrag h0n = H0F(j+1), h1n = H1F(j+1);
                bfrag a0n = U0F(j+2);
                T00 = MFMA32(a0A, h0, T00);
                T01 = MFMA32(a0A, h1, T01);
                if (has1) {
                    bfrag a1n = U1F(j+2);
                    T10 = MFMA32(a1A, h0, T10);
                    T11 = MFMA32(a1A, h1, T11);
                    a1A = a1B; a1B = a1n;
                }
                a0A = a0B; a0B = a0n;
                h0 = h0n; h1 = h1n;
            }
            {   // j = 23
                bfrag h0n = H0F(24), h1n = H1F(24);
                T00 = MFMA32(a0A, h0, T00);
                T01 = MFMA32(a0A, h1, T01);
                if (has1) {
                    T10 = MFMA32(a1A, h0, T10);
                    T11 = MFMA32(a1A, h1, T11);
                    a1A = a1B;
                }
                a0A = a0B; h0 = h0n; h1 = h1n;
            }
            {   // j = 24
                T00 = MFMA32(a0A, h0, T00);
                T01 = MFMA32(a0A, h1, T01);
                if (has1) {
                    T10 = MFMA32(a1A, h0, T10);
                    T11 = MFMA32(a1A, h1, T11);
                }
            }
#undef U0F
#undef U1F
#undef H0F
#undef H1F
        }
        __syncthreads();   // all waves done reading Ping-as-Hs

        if (p1on) {
            t_write(Ping, T00, 2*ep,   2*hp,   l31, kh);
            t_write(Ping, T01, 2*ep,   2*hp+1, l31, kh);
            if (has1) {
                t_write(Ping, T10, 2*ep+1, 2*hp,   l31, kh);
                t_write(Ping, T11, 2*ep+1, 2*hp+1, l31, kh);
            }
        }
        __syncthreads();   // Tbuf complete

        // ---- Phase 2: one 32x32 S-tile per wave, 25 K-steps (e<400) ----
        ffrag S; fzero(S);
        const short* ta = Ping + ((size_t)kh*LL + 32*ht2 + l31)*8;
        const short* cp = Cs + (csB + (size_t)kh*LL + 32*ct + l31)*8;
#define TAF(j) (*(const bfrag*)(ta + (size_t)(2*(j))*(LL*8)))
#define CPF(j) (*(const bfrag*)(cp + (size_t)(2*(j))*(LL*8)))
        bfrag c0f=CPF(0), c1f=CPF(1), c2f=CPF(2), c3f=CPF(3), c4f=CPF(4), c5f=CPF(5);
        bfrag t0f=TAF(0), t1f=TAF(1), t2f=TAF(2);
#pragma unroll 1
        for (int j = 0; j < 19; ++j) {       // consumes (t0,c0); loads j+6 / j+3
            bfrag cn = CPF(j+6), tn = TAF(j+3);
            S = MFMA32(t0f, c0f, S);
            t0f=t1f; t1f=t2f; t2f=tn;
            c0f=c1f; c1f=c2f; c2f=c3f; c3f=c4f; c4f=c5f; c5f=cn;
        }
#pragma unroll 1
        for (int j = 19; j < 22; ++j) {      // loads TAF(j+3) only (22..24)
            bfrag tn = TAF(j+3);
            S = MFMA32(t0f, c0f, S);
            t0f=t1f; t1f=t2f; t2f=tn;
            c0f=c1f; c1f=c2f; c2f=c3f; c3f=c4f;
        }
        S = MFMA32(t0f, c0f, S); t0f=t1f; c0f=c1f; t1f=t2f; c1f=c2f;   // j=22
        S = MFMA32(t0f, c0f, S); t0f=t1f; c0f=c1f;                      // j=23
        S = MFMA32(t0f, c0f, S);                                        // j=24
#undef TAF
#undef CPF

        // ---- per-k epilogue ----
        const float bk = bvec[k];
        const float* SDb = SD + ((size_t)b*KK + k)*LL;
        const float sev = SE[((size_t)b*KK + k)*LL + c0];
#pragma unroll
        for (int r = 0; r < 16; ++r) {
            const int hr = hbase + (r&3) + 8*(r>>2);
            const float ev = S[r] + SDb[hr] + sev + bk;
            if ((vb >> r) & 1) {
                E[r] += __expf(ev);
                if (c0 >= 1 && tag0 == k && head0 == hr) atomicAdd(&tgt[b], ev);
            }
        }
    }

    // ---- write slice g (exclusive ownership, non-atomic) ----
    float* Ab = A8 + ((size_t)(g*BB + b))*LL*LL;
#pragma unroll
    for (int r = 0; r < 16; ++r) {
        const int hr = hbase + (r&3) + 8*(r>>2);
        Ab[hr*LL + c0] = E[r];
    }
}

// ---------------------------------------------------------------------------
// k_sum: parallel 8-slice sum + column partial sums.
// grid 32*16 blocks (16 per b, 8 rows each), 256 thr, 1 float4/thread.
// ---------------------------------------------------------------------------
__global__ __launch_bounds__(256) void k_sum(
    const float* __restrict__ A8, float* __restrict__ Asum,
    float* __restrict__ Dgw)
{
    const int b = blockIdx.x >> 4;
    const int seg = blockIdx.x & 15;
    const int t = threadIdx.x;
    __shared__ float cs[128];
    if (t < 128) cs[t] = 0.f;
    __syncthreads();

    const int f4 = seg*256 + t;            // [0,4096): row = f4>>5, col4 = f4&31
    float4 s = make_float4(0.f, 0.f, 0.f, 0.f);
#pragma unroll
    for (int g = 0; g < 8; ++g) {
        float4 v = ((const float4*)A8)[((size_t)(g*BB + b))*4096 + f4];
        s.x += v.x; s.y += v.y; s.z += v.z; s.w += v.w;
    }
    ((float4*)Asum)[(size_t)b*4096 + f4] = s;

    const int c4 = (f4 & 31) * 4;
    atomicAdd(&cs[c4+0], s.x);
    atomicAdd(&cs[c4+1], s.y);
    atomicAdd(&cs[c4+2], s.z);
    atomicAdd(&cs[c4+3], s.w);
    __syncthreads();
    if (t < 128) atomicAdd(&Dgw[b*128 + t], cs[t]);
}

// ---------------------------------------------------------------------------
// Register-resident LU logdet, round 9:
//   - reads pre-summed Asum (64 KB/block, was 512 KB) + Dgw colsums
//   - LU loops j < n1 only (pivots beyond are identity, pivot = 1, log 0)
//   - double-buffered L/U publish: ONE barrier per pivot (was two)
//   - threads fully outside the active n1 x n1 region skip the update
// ---------------------------------------------------------------------------
__global__ __launch_bounds__(256) void k_logdet(
    const float* __restrict__ Asum, const float* __restrict__ Dgw,
    const int* __restrict__ lengths,
    const float* __restrict__ tgt, float* __restrict__ out)
{
    const int b = blockIdx.x;
    const int t = threadIdx.x;
    const int rg = t >> 4;
    const int cg = t & 15;

    __shared__ float As[LL*LL];     // 64 KB
    __shared__ float DgS[128];      // scaled colsums, then pivot stash
    __shared__ float Lb[2][128];
    __shared__ float Ub[2][128];
    __shared__ float red[256];

    {
        const float4* A4 = (const float4*)(Asum + (size_t)b*LL*LL);
        for (int i = t; i < 4096; i += 256) ((float4*)As)[i] = A4[i];
    }
    if (t < 128) DgS[t] = Dgw[b*128 + t] * (1.0f + 1e-4f) + 1e-6f;
    __syncthreads();

    const int n1 = lengths[b] - 1;      // active Sub dimension (<= 127)
    float m[8][8];
#pragma unroll
    for (int r = 0; r < 8; ++r) {
        const int i = 8*rg + r;
#pragma unroll
        for (int c = 0; c < 8; ++c) {
            const int j = 8*cg + c;
            float v;
            if (i < n1 && j < n1)
                v = ((i == j) ? DgS[i+1] : 0.f) - As[(i+1)*LL + (j+1)];
            else
                v = (i == j) ? 1.f : 0.f;
            m[r][c] = v;
        }
    }
    __syncthreads();

    const bool act = (8*rg < n1) && (8*cg < n1);
    for (int j = 0; j < n1; ++j) {
        const int bu = j & 1, jg = j >> 3, jl = j & 7;
        if (cg == jg) {
#pragma unroll
            for (int c = 0; c < 8; ++c) {
                if (c == jl) {
#pragma unroll
                    for (int r = 0; r < 8; ++r) Lb[bu][8*rg + r] = m[r][c];
                }
            }
        }
        if (rg == jg) {
#pragma unroll
            for (int r = 0; r < 8; ++r) {
                if (r == jl) {
#pragma unroll
                    for (int c = 0; c < 8; ++c) Ub[bu][8*cg + c] = m[r][c];
                }
            }
        }
        __syncthreads();

        const float piv = Lb[bu][j];
        if (t == j) DgS[j] = piv;
        if (act) {
            const float rp = 1.0f / piv;
            float lr[8], ur[8];
#pragma unroll
            for (int r = 0; r < 8; ++r) lr[r] = Lb[bu][8*rg + r] * rp;
#pragma unroll
            for (int c = 0; c < 8; ++c) ur[c] = Ub[bu][8*cg + c];
#pragma unroll
            for (int r = 0; r < 8; ++r)
#pragma unroll
                for (int c = 0; c < 8; ++c)
                    m[r][c] = fmaf(-lr[r], ur[c], m[r][c]);
        }
        // no second barrier: next pivot publishes into the other buffer
    }
    __syncthreads();

    float lsum = 0.f;
    if (t < n1) lsum = logf(DgS[t]);
    red[t] = lsum;
    __syncthreads();
    for (int off = 128; off >= 1; off >>= 1) {
        if (t < off) red[t] += red[t + off];
        __syncthreads();
    }
    if (t == 0) out[b] = red[0] - tgt[b];
}

// ---------------------------------------------------------------------------
extern "C" void kernel_launch(void* const* d_in, const int* in_sizes, int n_in,
                              void* d_out, int out_size, void* d_ws, size_t ws_size,
                              hipStream_t stream) {
    const float* H    = (const float*)d_in[0];
    const float* C    = (const float*)d_in[1];
    const float* Wd   = (const float*)d_in[2];
    const float* We   = (const float*)d_in[3];
    const float* U    = (const float*)d_in[4];
    const float* bv   = (const float*)d_in[5];
    const float* mask = (const float*)d_in[6];
    const int* heads  = (const int*)d_in[7];
    const int* tags   = (const int*)d_in[8];
    const int* lens   = (const int*)d_in[9];
    float* out = (float*)d_out;

    // workspace layout
    char* p = (char*)d_ws;
    float* A8   = (float*)p;                p += (size_t)8*BB*LL*LL*4;      // 16.78 MB
    float* Asum = (float*)p;                p += (size_t)BB*LL*LL*4;        // 2.10 MB
    float* Dgw  = (float*)p;                p += (size_t)BB*128*4;
    float* tgt  = (float*)p;                p += 32*4;
    float* SDp  = (float*)p;                p += (size_t)BB*KK*LL*4;
    float* SEp  = (float*)p;                p += (size_t)BB*KK*LL*4;
    short* Hsp  = (short*)p;                p += (size_t)BB*SDN*LL*8*2;
    short* Csp  = (short*)p;                p += (size_t)BB*SEN*LL*8*2;
    short* Usp  = (short*)p;                p += (size_t)KK*SDN*EE*8*2;

    // (BB*SDN*LL + BB*SEN*LL + KK*SDN*EE) / 256 = 4882 exactly
    p_prep<<<dim3(4882), 256, 0, stream>>>(H, C, U, Hsp, Csp, Usp);
    k_sdse<<<dim3(BB, 4, 2), 256, 0, stream>>>(H, C, Wd, We, SDp, SEp, tgt, Dgw);
    // b on blockIdx.x (fast dim) -> XCD = b % 8
    k_mfma<<<dim3(BB, 8), 1024, 0, stream>>>(Hsp, Csp, Usp, SDp, SEp, bv, mask,
                                             heads, tags, A8, tgt);
    k_sum<<<dim3(BB*16), 256, 0, stream>>>(A8, Asum, Dgw);
    k_logdet<<<dim3(BB), 256, 0, stream>>>(Asum, Dgw, lens, tgt, out);
}

// Round 10
// 361.281 us; speedup vs baseline: 1.9456x; 1.9456x over previous
//
#include <hip/hip_runtime.h>
#include <hip/hip_bf16.h>

#define BB 32
#define LL 128
#define DD 400
#define KK 40
#define EE 416   // e padded to 13*32
#define SDN 50   // d-slot count (400/8)
#define SEN 52   // e-slot count (416/8)

typedef __attribute__((ext_vector_type(8)))  short  bfrag;   // 8 bf16 = 4 VGPRs
typedef __attribute__((ext_vector_type(16))) float  ffrag;   // 16 fp32 acc

static __device__ __forceinline__ short f2bf(float f) {
    union { float f; unsigned u; } v; v.f = f;
    unsigned r = (v.u + 0x7FFF + ((v.u >> 16) & 1)) >> 16;
    return (short)r;
}

#define MFMA32(a, b, c) __builtin_amdgcn_mfma_f32_32x32x16_bf16((a), (b), (c), 0, 0, 0)

static __device__ __forceinline__ void fzero(ffrag& f) {
#pragma unroll
    for (int r = 0; r < 16; ++r) f[r] = 0.f;
}

// ---------------------------------------------------------------------------
// Fused prep: Hslots[b][sd][h][8], Cslots[b][se][c][8] (zero-pad e>=400),
//             Uslots[k][sd][e][8] (zero-pad e>=400).
// ---------------------------------------------------------------------------
__global__ __launch_bounds__(256) void p_prep(
    const float* __restrict__ H, const float* __restrict__ C,
    const float* __restrict__ U,
    short* __restrict__ Hs, short* __restrict__ Cs, short* __restrict__ Us)
{
    int id = blockIdx.x * 256 + threadIdx.x;
    if (id < BB*SDN*LL) {
        int b = id / (SDN*LL); int r = id % (SDN*LL);
        int sd = r / LL; int h = r % LL;
        const float* src = H + ((size_t)(b*LL + h))*DD + sd*8;
        bfrag v;
#pragma unroll
        for (int j = 0; j < 8; ++j) v[j] = f2bf(src[j]);
        *(bfrag*)(Hs + (size_t)id*8) = v;
    } else if (id < BB*SDN*LL + BB*SEN*LL) {
        id -= BB*SDN*LL;
        int b = id / (SEN*LL); int r = id % (SEN*LL);
        int se = r / LL; int c = r % LL;
        bfrag v;
#pragma unroll
        for (int j = 0; j < 8; ++j) {
            int e = se*8 + j;
            v[j] = (e < DD) ? f2bf(C[((size_t)(b*LL + c))*DD + e]) : (short)0;
        }
        *(bfrag*)(Cs + (size_t)id*8) = v;
    } else {
        id -= BB*SDN*LL + BB*SEN*LL;      // < 40*50*416
        int k = id / (SDN*EE); int r = id % (SDN*EE);
        int sd = r / EE; int e = r % EE;
        bfrag v;
#pragma unroll
        for (int j = 0; j < 8; ++j)
            v[j] = (e < DD) ? f2bf(U[((size_t)k*DD + sd*8 + j)*DD + e]) : (short)0;
        *(bfrag*)(Us + (size_t)id*8) = v;
    }
}

// ---------------------------------------------------------------------------
// SD/SE (round-2-verified body). Also zeroes tgt and Dgw (stream-ordered
// before their consumers).
// ---------------------------------------------------------------------------
__global__ __launch_bounds__(256) void k_sdse(
    const float* __restrict__ H, const float* __restrict__ C,
    const float* __restrict__ Wd, const float* __restrict__ We,
    float* __restrict__ SD, float* __restrict__ SE,
    float* __restrict__ tgt, float* __restrict__ Dgw)
{
    const int b   = blockIdx.x;
    const int rg  = blockIdx.y;
    const int srcC = blockIdx.z;
    const int t = threadIdx.x;

    if (srcC == 0) {
        if (rg == 0 && t == 0) tgt[b] = 0.f;
        if (t < 32) Dgw[b*128 + rg*32 + t] = 0.f;
    }

    __shared__ float Wl[KK*DD];      // 64 KB
    {
        const float4* Wsrc = (const float4*)(srcC ? We : Wd);
        for (int i = t; i < KK*DD/4; i += 256) ((float4*)Wl)[i] = Wsrc[i];
    }
    __syncthreads();

    const int task = t >> 3;
    const int p    = t & 7;
    const int row  = rg*32 + task;
    const float* X = (srcC ? C : H) + ((size_t)(b*LL + row))*DD + p*50;

    float2 x[25];
#pragma unroll
    for (int i = 0; i < 25; ++i) x[i] = ((const float2*)X)[i];

    float* out = (srcC ? SE : SD) + (size_t)b*KK*LL + row;
    const float* Wb = Wl + p*50;

    for (int k = 0; k < KK; ++k) {
        const float2* wp = (const float2*)(Wb + k*DD);
        float s0 = 0.f, s1 = 0.f;
#pragma unroll
        for (int i = 0; i < 24; i += 2) {
            float2 w0 = wp[i], w1 = wp[i+1];
            s0 = fmaf(x[i].x,   w0.x, s0); s0 = fmaf(x[i].y,   w0.y, s0);
            s1 = fmaf(x[i+1].x, w1.x, s1); s1 = fmaf(x[i+1].y, w1.y, s1);
        }
        { float2 w0 = wp[24]; s0 = fmaf(x[24].x, w0.x, s0); s0 = fmaf(x[24].y, w0.y, s0); }
        float s = s0 + s1;
        s += __shfl_xor(s, 1); s += __shfl_xor(s, 2); s += __shfl_xor(s, 4);
        if (p == 0) out[k*LL] = s;
    }
}

// T-write: scatter one 32x32 T-tile into phase-2 A-fragment layout
// [s_e][h][8] as 4 x ds_write_b64 (round-8 verified). Skips e>=400.
static __device__ __forceinline__ void t_write(
    short* __restrict__ Ping, const ffrag& T, int et, int ht, int l31, int kh)
{
#pragma unroll
    for (int q = 0; q < 4; ++q) {
        const int e_base = 32*et + 8*q + 4*kh;   // e_loc = e_base + (0..3)
        if (e_base < DD) {
            const int r = 4*q;
            uint2 v;
            v.x = (unsigned)(unsigned short)f2bf(T[r])
                | ((unsigned)(unsigned short)f2bf(T[r+1]) << 16);
            v.y = (unsigned)(unsigned short)f2bf(T[r+2])
                | ((unsigned)(unsigned short)f2bf(T[r+3]) << 16);
            *(uint2*)(&Ping[((size_t)(e_base>>3)*LL + 32*ht + l31)*8 + (e_base&7)]) = v;
        }
    }
}

// ---------------------------------------------------------------------------
// Main MFMA kernel, round 10 = round-8 verified body with ONE change:
// phase-1 U (global) prefetch deepened 2 -> 5 via batched double-buffer
// (named regs u0..u4 / n0..n4, no dynamic indexing; #pragma unroll 1 on
// the group loop so the compiler cannot globally hoist like round 7).
// Rationale: Us misses L2 (FETCH ~= 8 XCD x 13.3 MB), ~900cy HBM latency
// over a 2-deep prefetch was the invariant ~19% MfmaUtil across r2/4/5/8.
// H reads stay point-of-use (r8 proved H-pipelining is null).
// Phase 2 byte-identical to round 8 (verified; round-9's edit was the bug).
// ---------------------------------------------------------------------------
__global__ __launch_bounds__(1024) void k_mfma(
    const short* __restrict__ Hs, const short* __restrict__ Cs,
    const short* __restrict__ Us,
    const float* __restrict__ SD, const float* __restrict__ SE,
    const float* __restrict__ bvec, const float* __restrict__ mask,
    const int* __restrict__ heads, const int* __restrict__ tags,
    float* __restrict__ A8, float* __restrict__ tgt)
{
    const int b  = blockIdx.x;     // fast dim -> XCD = b % 8
    const int g  = blockIdx.y;     // k-group
    const int t  = threadIdx.x;
    const int w  = t >> 6;         // 0..15
    const int l31 = t & 31;
    const int kh  = (t >> 5) & 1;  // K-half of MFMA operands

    __shared__ short Ping[SDN*LL*8];    // 102,400 B : Hs stage <-> Tbuf

    const size_t hsB = (size_t)b * SDN * LL;
    const size_t csB = (size_t)b * SEN * LL;

    // ---- phase-2 roles & k-invariant epilogue constants ----
    const int ht2 = w >> 2;            // h-tile 0..3
    const int ct  = w & 3;             // c-tile 0..3
    const int hbase = 32*ht2 + 4*kh;
    const int c0 = 32*ct + l31;
    const float mc0 = mask[b*LL + c0];
    const int head0 = heads[b*LL + c0];
    const int tag0  = tags[b*LL + c0];
    unsigned vb = 0;
#pragma unroll
    for (int r = 0; r < 16; ++r) {
        const int hr = hbase + (r&3) + 8*(r>>2);
        if (mask[b*LL + hr] != 0.f && mc0 != 0.f && hr != c0) vb |= 1u << r;
    }

    ffrag E; fzero(E);

    for (int kk = 0; kk < 5; ++kk) {
        const int k = g + 8*kk;

        __syncthreads();   // prev phase 2 done reading Ping

        // ---- stage Hs[b] -> Ping (102.4 KB straight copy; L2-resident) ----
        {
            const uint4* src = (const uint4*)(Hs + hsB*8);
            uint4* dst = (uint4*)Ping;
            for (int i = t; i < SDN*LL*8*2/16; i += 1024) dst[i] = src[i];
        }
        __syncthreads();

        // ---- Phase 1: wave w<13 computes T[e-tile w][all 128 h] ----
        ffrag T0, T1, T2, T3;
        if (w < 13) {
            fzero(T0); fzero(T1); fzero(T2); fzero(T3);
            const int et = w;
            const short* up = Us + (((size_t)k*SDN + kh)*EE + 32*et + l31)*8;
            const short* hb = Ping + ((size_t)kh*LL + l31)*8;
#define UPF(j)    (*(const bfrag*)(up + (size_t)(j)*(2*EE*8)))
#define HPF(j,ht) (*(const bfrag*)(hb + ((size_t)(2*(j))*LL + 32*(ht))*8))
#define STEP(u,j) do { \
                bfrag b0 = HPF(j,0), b1 = HPF(j,1), b2 = HPF(j,2), b3 = HPF(j,3); \
                T0 = MFMA32(u, b0, T0); T1 = MFMA32(u, b1, T1); \
                T2 = MFMA32(u, b2, T2); T3 = MFMA32(u, b3, T3); } while(0)
            bfrag u0=UPF(0), u1=UPF(1), u2=UPF(2), u3=UPF(3), u4=UPF(4);
#pragma unroll 1
            for (int gq = 0; gq < 4; ++gq) {
                const int bs = 5*gq;
                bfrag n0=UPF(bs+5), n1=UPF(bs+6), n2=UPF(bs+7),
                      n3=UPF(bs+8), n4=UPF(bs+9);
                STEP(u0, bs+0);
                STEP(u1, bs+1);
                STEP(u2, bs+2);
                STEP(u3, bs+3);
                STEP(u4, bs+4);
                u0=n0; u1=n1; u2=n2; u3=n3; u4=n4;
            }
            STEP(u0, 20);
            STEP(u1, 21);
            STEP(u2, 22);
            STEP(u3, 23);
            STEP(u4, 24);
#undef STEP
#undef UPF
#undef HPF
        }
        __syncthreads();   // all waves done reading Ping-as-Hs

        if (w < 13) {
            t_write(Ping, T0, w, 0, l31, kh);
            t_write(Ping, T1, w, 1, l31, kh);
            t_write(Ping, T2, w, 2, l31, kh);
            t_write(Ping, T3, w, 3, l31, kh);
        }
        __syncthreads();   // Tbuf complete

        // ---- Phase 2: one 32x32 S-tile per wave, 25 K-steps (e<400) ----
        // (byte-identical to round 8 — verified correct)
        ffrag S; fzero(S);
        const short* ta = Ping + ((size_t)kh*LL + 32*ht2 + l31)*8;
        const short* cp = Cs + (csB + (size_t)kh*LL + 32*ct + l31)*8;
#define TAF(j) (*(const bfrag*)(ta + (size_t)(2*(j))*(LL*8)))
#define CPF(j) (*(const bfrag*)(cp + (size_t)(2*(j))*(LL*8)))
        bfrag c0f = CPF(0), c1f = CPF(1), c2f = CPF(2);
        bfrag t0f = TAF(0), t1f = TAF(1);
#pragma unroll 1
        for (int j = 0; j < 22; ++j) {
            bfrag cn = CPF(j+3);
            bfrag tn = TAF(j+2);
            S = MFMA32(t0f, c0f, S);
            t0f = t1f; t1f = tn;
            c0f = c1f; c1f = c2f; c2f = cn;
        }
        S = MFMA32(t0f, c0f, S);          // j = 22
        S = MFMA32(t1f, c1f, S);          // j = 23
        S = MFMA32(TAF(24), c2f, S);      // j = 24
#undef TAF
#undef CPF

        // ---- per-k epilogue ----
        const float bk = bvec[k];
        const float* SDb = SD + ((size_t)b*KK + k)*LL;
        const float sev = SE[((size_t)b*KK + k)*LL + c0];
#pragma unroll
        for (int r = 0; r < 16; ++r) {
            const int hr = hbase + (r&3) + 8*(r>>2);
            const float ev = S[r] + SDb[hr] + sev + bk;
            if ((vb >> r) & 1) {
                E[r] += __expf(ev);
                if (c0 >= 1 && tag0 == k && head0 == hr) atomicAdd(&tgt[b], ev);
            }
        }
    }

    // ---- write slice g (exclusive ownership, non-atomic) ----
    float* Ab = A8 + ((size_t)(g*BB + b))*LL*LL;
#pragma unroll
    for (int r = 0; r < 16; ++r) {
        const int hr = hbase + (r&3) + 8*(r>>2);
        Ab[hr*LL + c0] = E[r];
    }
}

// ---------------------------------------------------------------------------
// k_sum: parallel 8-slice sum + column partial sums.
// grid 32*16 blocks, 256 thr, 1 float4/thread.
// ---------------------------------------------------------------------------
__global__ __launch_bounds__(256) void k_sum(
    const float* __restrict__ A8, float* __restrict__ Asum,
    float* __restrict__ Dgw)
{
    const int b = blockIdx.x >> 4;
    const int seg = blockIdx.x & 15;
    const int t = threadIdx.x;
    __shared__ float cs[128];
    if (t < 128) cs[t] = 0.f;
    __syncthreads();

    const int f4 = seg*256 + t;            // [0,4096): row = f4>>5, col4 = f4&31
    float4 s = make_float4(0.f, 0.f, 0.f, 0.f);
#pragma unroll
    for (int g = 0; g < 8; ++g) {
        float4 v = ((const float4*)A8)[((size_t)(g*BB + b))*4096 + f4];
        s.x += v.x; s.y += v.y; s.z += v.z; s.w += v.w;
    }
    ((float4*)Asum)[(size_t)b*4096 + f4] = s;

    const int c4 = (f4 & 31) * 4;
    atomicAdd(&cs[c4+0], s.x);
    atomicAdd(&cs[c4+1], s.y);
    atomicAdd(&cs[c4+2], s.z);
    atomicAdd(&cs[c4+3], s.w);
    __syncthreads();
    if (t < 128) atomicAdd(&Dgw[b*128 + t], cs[t]);
}

// ---------------------------------------------------------------------------
// Register-resident LU logdet (round-9 design; race analysis redone):
//   - reads pre-summed Asum (64 KB/block) + Dgw colsums
//   - LU loops j < n1 only (identity pivots contribute log 1 = 0)
//   - double-buffered L/U publish: ONE barrier per pivot. Publish(j+1)
//     writes buffer (j+1)&1 while laggards of update(j) read buffer j&1;
//     re-write of buffer j&1 at publish(j+2) is ordered by barrier(j+1).
// ---------------------------------------------------------------------------
__global__ __launch_bounds__(256) void k_logdet(
    const float* __restrict__ Asum, const float* __restrict__ Dgw,
    const int* __restrict__ lengths,
    const float* __restrict__ tgt, float* __restrict__ out)
{
    const int b = blockIdx.x;
    const int t = threadIdx.x;
    const int rg = t >> 4;
    const int cg = t & 15;

    __shared__ float As[LL*LL];     // 64 KB
    __shared__ float DgS[128];      // scaled colsums, then pivot stash
    __shared__ float Lb[2][128];
    __shared__ float Ub[2][128];
    __shared__ float red[256];

    {
        const float4* A4 = (const float4*)(Asum + (size_t)b*LL*LL);
        for (int i = t; i < 4096; i += 256) ((float4*)As)[i] = A4[i];
    }
    if (t < 128) DgS[t] = Dgw[b*128 + t] * (1.0f + 1e-4f) + 1e-6f;
    __syncthreads();

    const int n1 = lengths[b] - 1;      // active Sub dimension (<= 127)
    float m[8][8];
#pragma unroll
    for (int r = 0; r < 8; ++r) {
        const int i = 8*rg + r;
#pragma unroll
        for (int c = 0; c < 8; ++c) {
            const int j = 8*cg + c;
            float v;
            if (i < n1 && j < n1)
                v = ((i == j) ? DgS[i+1] : 0.f) - As[(i+1)*LL + (j+1)];
            else
                v = (i == j) ? 1.f : 0.f;
            m[r][c] = v;
        }
    }
    __syncthreads();

    const bool act = (8*rg < n1) && (8*cg < n1);
    for (int j = 0; j < n1; ++j) {
        const int bu = j & 1, jg = j >> 3, jl = j & 7;
        if (cg == jg) {
#pragma unroll
            for (int c = 0; c < 8; ++c) {
                if (c == jl) {
#pragma unroll
                    for (int r = 0; r < 8; ++r) Lb[bu][8*rg + r] = m[r][c];
                }
            }
        }
        if (rg == jg) {
#pragma unroll
            for (int r = 0; r < 8; ++r) {
                if (r == jl) {
#pragma unroll
                    for (int c = 0; c < 8; ++c) Ub[bu][8*cg + c] = m[r][c];
                }
            }
        }
        __syncthreads();

        const float piv = Lb[bu][j];
        if (t == j) DgS[j] = piv;
        if (act) {
            const float rp = 1.0f / piv;
            float lr[8], ur[8];
#pragma unroll
            for (int r = 0; r < 8; ++r) lr[r] = Lb[bu][8*rg + r] * rp;
#pragma unroll
            for (int c = 0; c < 8; ++c) ur[c] = Ub[bu][8*cg + c];
#pragma unroll
            for (int r = 0; r < 8; ++r)
#pragma unroll
                for (int c = 0; c < 8; ++c)
                    m[r][c] = fmaf(-lr[r], ur[c], m[r][c]);
        }
    }
    __syncthreads();

    float lsum = 0.f;
    if (t < n1) lsum = logf(DgS[t]);
    red[t] = lsum;
    __syncthreads();
    for (int off = 128; off >= 1; off >>= 1) {
        if (t < off) red[t] += red[t + off];
        __syncthreads();
    }
    if (t == 0) out[b] = red[0] - tgt[b];
}

// ---------------------------------------------------------------------------
extern "C" void kernel_launch(void* const* d_in, const int* in_sizes, int n_in,
                              void* d_out, int out_size, void* d_ws, size_t ws_size,
                              hipStream_t stream) {
    const float* H    = (const float*)d_in[0];
    const float* C    = (const float*)d_in[1];
    const float* Wd   = (const float*)d_in[2];
    const float* We   = (const float*)d_in[3];
    const float* U    = (const float*)d_in[4];
    const float* bv   = (const float*)d_in[5];
    const float* mask = (const float*)d_in[6];
    const int* heads  = (const int*)d_in[7];
    const int* tags   = (const int*)d_in[8];
    const int* lens   = (const int*)d_in[9];
    float* out = (float*)d_out;

    // workspace layout
    char* p = (char*)d_ws;
    float* A8   = (float*)p;                p += (size_t)8*BB*LL*LL*4;      // 16.78 MB
    float* Asum = (float*)p;                p += (size_t)BB*LL*LL*4;        // 2.10 MB
    float* Dgw  = (float*)p;                p += (size_t)BB*128*4;
    float* tgt  = (float*)p;                p += 32*4;
    float* SDp  = (float*)p;                p += (size_t)BB*KK*LL*4;
    float* SEp  = (float*)p;                p += (size_t)BB*KK*LL*4;
    short* Hsp  = (short*)p;                p += (size_t)BB*SDN*LL*8*2;
    short* Csp  = (short*)p;                p += (size_t)BB*SEN*LL*8*2;
    short* Usp  = (short*)p;                p += (size_t)KK*SDN*EE*8*2;

    // (BB*SDN*LL + BB*SEN*LL + KK*SDN*EE) / 256 = 4882 exactly
    p_prep<<<dim3(4882), 256, 0, stream>>>(H, C, U, Hsp, Csp, Usp);
    k_sdse<<<dim3(BB, 4, 2), 256, 0, stream>>>(H, C, Wd, We, SDp, SEp, tgt, Dgw);
    // b on blockIdx.x (fast dim) -> XCD = b % 8
    k_mfma<<<dim3(BB, 8), 1024, 0, stream>>>(Hsp, Csp, Usp, SDp, SEp, bv, mask,
                                             heads, tags, A8, tgt);
    k_sum<<<dim3(BB*16), 256, 0, stream>>>(A8, Asum, Dgw);
    k_logdet<<<dim3(BB), 256, 0, stream>>>(Asum, Dgw, lens, tgt, out);
}